// Round 10
// baseline (7466.486 us; speedup 1.0000x reference)
//
#include <hip/hip_runtime.h>
#include <cstdint>
#include <cstddef>

// R10: dual-ring slice exchange — R9 with the FAST_CAP earliness bug fixed.
// R9's cap=12 was exhausted ~500cy into the step, before any sibling had
// published (~1-4us) -> every lane fell back at t=2 and the fast path was
// never exercised. Cap is now 6000 polls (~250us one-time worst case, still
// bounded -> hang-impossible), so a genuine co-located fast ring hits within
// a few polls every step, and only true incoherence/misplacement triggers
// permanent per-lane fallback to the R4-proven MALL ring.
// Everything else identical to R9: epoch-tagged words (replay-safe), bf16-pair
// packing, x register prefetch, conflict-free out-proj, one barrier/step.

#define BB 64
#define TT 1024
#define II 64
#define HH 512
#define OO 64
#define FAST_CAP 6000

__device__ __forceinline__ float tanh_fast(float v) {
  float e = exp2f(fabsf(v) * 2.8853900817779268f);
  float r = 1.0f - 2.0f * __builtin_amdgcn_rcpf(e + 1.0f);
  return copysignf(r, v);
}
__device__ __forceinline__ unsigned f2bf(float f) {  // RTNE
  unsigned u = __float_as_uint(f);
  return (u + 0x7fffu + ((u >> 16) & 1u)) >> 16;
}
__device__ __forceinline__ float bf2f(unsigned b) {
  return __uint_as_float(b << 16);
}
__device__ __forceinline__ unsigned long long ld_sc0(const unsigned long long* p) {
  unsigned long long v;
  asm volatile("global_load_dwordx2 %0, %1, off sc0\n\ts_waitcnt vmcnt(0)"
               : "=v"(v) : "v"(p) : "memory");
  return v;
}
__device__ __forceinline__ void st_sc0(unsigned long long* p, unsigned long long w) {
  asm volatile("global_store_dwordx2 %0, %1, off sc0"
               :: "v"(p), "v"(w) : "memory");
}

__global__ __launch_bounds__(512, 1) void rnn_persist(
    const float* __restrict__ x, const float* __restrict__ h0,
    const float* __restrict__ Wih, const float* __restrict__ Whh,
    const float* __restrict__ bih, const float* __restrict__ bhh,
    const float* __restrict__ Wout, const float* __restrict__ bout,
    float* __restrict__ out, unsigned long long* __restrict__ epoch_cell,
    unsigned* __restrict__ epoch_bcast,
    unsigned long long* __restrict__ slowring,
    unsigned long long* __restrict__ fastring) {
  const int tid = threadIdx.x;
  const int b   = blockIdx.x & 63;   // batch element
  const int q   = blockIdx.x >> 6;   // slice quarter
  const int n   = tid >> 2;          // local output row 0..127
  const int q4  = tid & 3;           // k-quarter (128 k's each)
  const int row = q * 128 + n;       // global row in H

  __shared__ float h2[2][4][132];
  __shared__ float x2[2][II];
  __shared__ unsigned s_epoch;

  // ---- register-resident weights ----
  float wh[128];
#pragma unroll
  for (int j = 0; j < 32; ++j) {
    const float4 v = *(const float4*)(Whh + (size_t)row * HH + q4 * 128 + j * 4);
    wh[4*j+0] = v.x; wh[4*j+1] = v.y; wh[4*j+2] = v.z; wh[4*j+3] = v.w;
  }
  float wi[16];
#pragma unroll
  for (int j = 0; j < 4; ++j) {
    const float4 v = *(const float4*)(Wih + (size_t)row * II + q4 * 16 + j * 4);
    wi[4*j+0] = v.x; wi[4*j+1] = v.y; wi[4*j+2] = v.z; wi[4*j+3] = v.w;
  }
  const float bias_n = bih[row] + bhh[row];

  // out-proj weights: waves 0-3 only; lane oc covers k=16j+oc (conflict-free)
  const int l     = tid & 63;
  const int oc    = l & 15;
  const int o_loc = (tid >> 6) * 4 + (l >> 4);
  float wo[32];
  float bo = 0.0f;
  if (tid < 256) {
    const int o = q * 16 + o_loc;
#pragma unroll
    for (int j = 0; j < 32; ++j) wo[j] = Wout[(size_t)o * HH + oc + 16 * j];
    bo = bout[o];
  }

  // ---- per-launch epoch: persistent counter + zeroed broadcast cell ----
  if (tid == 0) {
    if (blockIdx.x == 0) {
      unsigned long long old = __hip_atomic_fetch_add(
          epoch_cell, 1ull, __ATOMIC_RELAXED, __HIP_MEMORY_SCOPE_AGENT);
      const unsigned e = (unsigned)old & 0xFFFFFu;
      __hip_atomic_store(epoch_bcast, (e << 1) | 1u,
                         __ATOMIC_RELAXED, __HIP_MEMORY_SCOPE_AGENT);
      s_epoch = e;
    } else {
      unsigned v;
      for (;;) {
        v = __hip_atomic_load(epoch_bcast, __ATOMIC_RELAXED,
                              __HIP_MEMORY_SCOPE_AGENT);
        if (v) break;
        __builtin_amdgcn_s_sleep(4);
      }
      s_epoch = v >> 1;
    }
  }
  __syncthreads();
  const unsigned epoch = s_epoch;

  const float* xb           = x + (size_t)b * TT * II;
  unsigned long long* slowb = slowring + (size_t)b * 2 * 256;
  unsigned long long* fastb = fastring + (size_t)b * 2 * 256;
  float* outb               = out + (size_t)b * TT * OO;

  const bool xloader = (tid >= 256 && tid < 272);
  if (xloader) {
    const int j = tid - 256;
    *(float4*)&x2[1][j * 4] = *(const float4*)(xb + j * 4);
  }

  bool fw = true;  // per-lane: fast ring still trusted

  for (int t = 1; t <= TT + 1; ++t) {
    const int hs = (t - 1) & 1;  // LDS/ring slot holding h_{t-1}

    // prefetch x[t] into registers (consumed at step t+1)
    float4 xv;
    if (t < TT && xloader) {
      xv = *(const float4*)(xb + (size_t)t * II + (tid - 256) * 4);
    }

    // stage h_{t-1}: tid<192 each poll ONE packed word of a sibling quarter
    if (t == 1) {
      if (tid < 256) {
        const int e0 = tid * 2;
        const float2 hv = *(const float2*)(h0 + (size_t)b * HH + e0);
        h2[0][tid >> 6][e0 & 127]       = hv.x;
        h2[0][tid >> 6][(e0 & 127) + 1] = hv.y;
      }
    } else if (tid < 192) {
      const int wq = tid >> 6;
      const int w  = wq + (wq >= q);   // skip own quarter
      const int m  = tid & 63;         // packed rows 2m, 2m+1 of quarter w
      const unsigned want = (epoch << 11) | (unsigned)(t - 1);
      const size_t off = (size_t)hs * 256 + (size_t)w * 64 + m;
      unsigned long long v = 0;
      bool got = false;
      if (fw) {  // bounded fast phase: local-L2 sc0 polls (cap = real timeout)
        for (int k2 = 0; k2 < FAST_CAP; ++k2) {
          v = ld_sc0(fastb + off);
          if ((unsigned)(v >> 32) == want) { got = true; break; }
        }
        if (!got) fw = false;  // genuine timeout -> permanent per-lane fallback
      }
      if (!got) {  // slow phase: agent-scope at the MALL (R4-proven)
        do {
          v = __hip_atomic_load(slowb + off, __ATOMIC_RELAXED,
                                __HIP_MEMORY_SCOPE_AGENT);
        } while ((unsigned)(v >> 32) != want);
      }
      const unsigned lo = (unsigned)v & 0xffffu;
      const unsigned hi = ((unsigned)v >> 16) & 0xffffu;
      *(float2*)&h2[hs][w][2 * m] = make_float2(bf2f(lo), bf2f(hi));
    }
    __syncthreads();

    // write prefetched x to LDS slot (t+1)&1 — hidden under compute
    if (t < TT && xloader) {
      *(float4*)&x2[(t + 1) & 1][(tid - 256) * 4] = xv;
    }

    if (t <= TT) {
      // ---- recurrent matvec: this thread's 128-k chunk of row `row` ----
      const float* hp = &h2[hs][q4][0];
      float a0 = 0.f, a1 = 0.f, a2 = 0.f, a3 = 0.f;
#pragma unroll
      for (int j = 0; j < 128; j += 4) {
        a0 = fmaf(wh[j+0], hp[j+0], a0);
        a1 = fmaf(wh[j+1], hp[j+1], a1);
        a2 = fmaf(wh[j+2], hp[j+2], a2);
        a3 = fmaf(wh[j+3], hp[j+3], a3);
      }
      // ---- input projection ----
      float ax = 0.f;
      const float* xp = &x2[t & 1][q4 * 16];
#pragma unroll
      for (int j = 0; j < 16; ++j) ax = fmaf(wi[j], xp[j], ax);

      float a = (a0 + a1) + (a2 + a3) + ax;
      a += __shfl_xor(a, 1);
      a += __shfl_xor(a, 2);
      const float hnew = tanh_fast(a + bias_n);
      const float pv   = __shfl_xor(hnew, 4);  // partner row (n^1)
      if (q4 == 0) {
        h2[t & 1][q][n] = hnew;  // own quarter, fp32, straight into next slot
        if ((n & 1) == 0) {
          const unsigned packed = f2bf(hnew) | (f2bf(pv) << 16);
          const unsigned long long word =
              ((unsigned long long)((epoch << 11) | (unsigned)t) << 32) |
              packed;
          const size_t off = (size_t)(t & 1) * 256 + (size_t)q * 64 + (n >> 1);
          st_sc0(fastb + off, word);                     // local L2 (fast)
          __hip_atomic_store(slowb + off, word,          // MALL (guaranteed)
                             __ATOMIC_RELAXED, __HIP_MEMORY_SCOPE_AGENT);
        }
      }
    }

    // ---- out-projection for tau = t-2 (off the critical path) ----
    if (t >= 2 && tid < 256) {
      float s0 = 0.f, s1 = 0.f;
#pragma unroll
      for (int j = 0; j < 32; j += 2) {
        s0 = fmaf(wo[j+0], h2[hs][(j+0) >> 3][oc + 16 * ((j+0) & 7)], s0);
        s1 = fmaf(wo[j+1], h2[hs][(j+1) >> 3][oc + 16 * ((j+1) & 7)], s1);
      }
      float s = s0 + s1;
      s += __shfl_xor(s, 1);
      s += __shfl_xor(s, 2);
      s += __shfl_xor(s, 4);
      s += __shfl_xor(s, 8);
      if (oc == 0) {
        outb[(size_t)(t - 2) * OO + q * 16 + o_loc] = tanh_fast(s + bo);
      }
    }

    // ---- final hidden state h_T -> d_out tail ----
    if (t == TT + 1 && q == 0 && tid < 256) {
      const int e0 = tid * 2;
      float* hout = out + (size_t)BB * TT * OO + (size_t)b * HH + e0;
      hout[0] = h2[hs][e0 >> 7][e0 & 127];
      hout[1] = h2[hs][e0 >> 7][(e0 & 127) + 1];
    }
  }
}

extern "C" void kernel_launch(void* const* d_in, const int* in_sizes, int n_in,
                              void* d_out, int out_size, void* d_ws, size_t ws_size,
                              hipStream_t stream) {
  (void)in_sizes; (void)n_in; (void)out_size; (void)ws_size;
  const float* x    = (const float*)d_in[0];
  const float* h0   = (const float*)d_in[1];
  const float* Wih  = (const float*)d_in[2];
  const float* Whh  = (const float*)d_in[3];
  const float* bih  = (const float*)d_in[4];
  const float* bhh  = (const float*)d_in[5];
  const float* Wout = (const float*)d_in[6];
  const float* bout = (const float*)d_in[7];
  float* out = (float*)d_out;

  unsigned char* ws = (unsigned char*)d_ws;
  // layout: [0]   epoch_cell   (8B, PERSISTENT — never memset)
  //         [256] epoch_bcast  (4B, zeroed every launch)
  //         [4096]          slow ring: 64b x 2 x 256 x 8B = 256 KB (zeroed)
  //         [4096 + 256KB]  fast ring: same size (epoch-tag protected)
  unsigned long long* epoch_cell = (unsigned long long*)ws;
  unsigned* epoch_bcast          = (unsigned*)(ws + 256);
  unsigned long long* slowring   = (unsigned long long*)(ws + 4096);
  unsigned long long* fastring   = (unsigned long long*)(ws + 4096 + 262144);

  // zero broadcast cell + slow-ring tags each (replayed) launch
  hipMemsetAsync(ws + 256, 0, 4096 - 256 + 262144, stream);

  rnn_persist<<<dim3(256), dim3(512), 0, stream>>>(
      x, h0, Wih, Whh, bih, bhh, Wout, bout, out,
      epoch_cell, epoch_bcast, slowring, fastring);
}

// Round 12
// 5481.343 us; speedup vs baseline: 1.3622x; 1.3622x over previous
//
#include <hip/hip_runtime.h>
#include <cstdint>
#include <cstddef>

// R12: R11 with the h2_t type fixed (__fp16 vector, matching
// __builtin_amdgcn_cvt_pkrtz / __builtin_amdgcn_fdot2 signatures).
//
// Single-CU-per-batch RNN — NO inter-WG communication at all.
// Lesson from R5/R6/R10: the XCD-local fast path never engages; cross-WG
// exchange is pinned at the ~5-8k cy MALL edge. So eliminate the exchange:
// W_hh in f16 fits ONE CU (512 thr x 192 packed-u32 VGPRs = 384KB + 128KB
// LDS tail = 512KB). 64 WGs = 1 per batch, 512 threads. h double-buffered in
// LDS; ONE barrier per step; zero atomics; hang-impossible by construction.
// Thread (g=tid>>3, c=tid&7): rows 8g..8g+7, k-chunk [64c,64c+64).
//   48 k/row from regs, 16 k/row from LDS. Reduce over c via shfl_xor.
//   Thread tid finalizes row tid, adds x-projection (Wih f16 slice from ws,
//   L1/L2-resident) + bias, tanh.
// Out-projection for t-1 overlaps step t (reads the still-live h slot).
// Prep kernel packs Wih/Wout to f16 (idempotent, replay-safe).

#define BB 64
#define TT 1024
#define II 64
#define HH 512
#define OO 64

typedef __fp16 h2_t __attribute__((ext_vector_type(2)));

__device__ __forceinline__ unsigned pk16(float a, float b) {
  h2_t h = __builtin_amdgcn_cvt_pkrtz(a, b);
  return __builtin_bit_cast(unsigned, h);
}

__device__ __forceinline__ float fdot2u(unsigned a, unsigned b, float c) {
#if __has_builtin(__builtin_amdgcn_fdot2)
  return __builtin_amdgcn_fdot2(__builtin_bit_cast(h2_t, a),
                                __builtin_bit_cast(h2_t, b), c, false);
#else
  h2_t x = __builtin_bit_cast(h2_t, a), y = __builtin_bit_cast(h2_t, b);
  return c + (float)x[0] * (float)y[0] + (float)x[1] * (float)y[1];
#endif
}

__device__ __forceinline__ float tanh_fast(float v) {
  float e = exp2f(fabsf(v) * 2.8853900817779268f);
  float r = 1.0f - 2.0f * __builtin_amdgcn_rcpf(e + 1.0f);
  return copysignf(r, v);
}

// ---- prep: pack Wih [512x64] and Wout [64x512] fp32 -> f16-pair u32 ----
__global__ void prep_pack(const float* __restrict__ Wih,
                          const float* __restrict__ Wout,
                          unsigned* __restrict__ wsWih,
                          unsigned* __restrict__ wsWout) {
  const int i = blockIdx.x * 256 + threadIdx.x;  // 0..32767
  if (i < 16384) {            // Wih: r = i>>5, pair m = i&31
    const float2 v = *(const float2*)(Wih + (size_t)(i >> 5) * II + (i & 31) * 2);
    wsWih[i] = pk16(v.x, v.y);
  } else {                    // Wout: o = k>>8, pair m = k&255
    const int k = i - 16384;
    const float2 v = *(const float2*)(Wout + (size_t)(k >> 8) * HH + (k & 255) * 2);
    wsWout[k] = pk16(v.x, v.y);
  }
}

__global__ __launch_bounds__(512, 1) void rnn_onecu(
    const float* __restrict__ x, const float* __restrict__ h0,
    const float* __restrict__ Whh, const float* __restrict__ bih,
    const float* __restrict__ bhh, const float* __restrict__ bout,
    const unsigned* __restrict__ wsWih, const unsigned* __restrict__ wsWout,
    float* __restrict__ out) {
  const int tid = threadIdx.x;
  const int b   = blockIdx.x;
  const int g   = tid >> 3;   // row-group: rows 8g..8g+7
  const int c   = tid & 7;    // k-chunk: k in [64c, 64c+64)

  // LDS: Whh tail (16 k/row) + h double-buffer (f16 pairs, padded chunks) + x
  __shared__ unsigned ldsW[16][512][4];   // 128 KB
  __shared__ unsigned hsl[2][8][36];      // [slot][chunk][32 used + 4 pad]
  __shared__ unsigned xsl[2][32];         // x[t] as f16 pairs

  // ---- prologue: Whh rows -> f16 pairs: 24 u32/row regs + 8 u32/row LDS ----
  unsigned wh[8][24];
#pragma unroll
  for (int j = 0; j < 8; ++j) {
    const float* base = Whh + (size_t)(8 * g + j) * HH + c * 64;
#pragma unroll
    for (int m = 0; m < 32; ++m) {
      const float2 w2 = *(const float2*)(base + 2 * m);
      const unsigned pw = pk16(w2.x, w2.y);
      if (m < 24) {
        wh[j][m] = pw;
      } else {
        const int flat = j * 8 + (m - 24);          // 0..63
        ldsW[flat >> 2][tid][flat & 3] = pw;
      }
    }
  }
  const float bsum = bih[tid] + bhh[tid];   // thread finalizes row `tid`
  const float bo   = bout[tid >> 3];        // for out-proj lanes (kc==0 uses)

  // stage h0 (f16 pairs) into slot 0
  {
    const float v  = h0[(size_t)b * HH + tid];
    const float pv = __shfl_xor(v, 1);
    if (!(tid & 1)) {
      const int m = tid >> 1;
      hsl[0][m >> 5][m & 31] = pk16(v, pv);
    }
  }
  // pre-stage x[0] into slot 1 (consumed at t=1)
  const bool xloader = (tid >= 448 && tid < 464);
  const int  xl      = tid - 448;
  if (xloader) {
    const float4 v = *(const float4*)(x + (size_t)b * TT * II + xl * 4);
    xsl[1][xl * 2]     = pk16(v.x, v.y);
    xsl[1][xl * 2 + 1] = pk16(v.z, v.w);
  }
  __syncthreads();

  const unsigned* wip = wsWih + tid * 32;               // this row's Wih slice
  const unsigned* wop = wsWout + (tid >> 3) * 256 + (tid & 7) * 32;
  float* outb = out + (size_t)b * TT * OO;

  for (int t = 1; t <= TT + 1; ++t) {
    const int p = (t - 1) & 1;   // h_{t-1} slot; x[t-1] is in slot t&1 = 1-p

    // prefetch+stage x[t] into slot (t+1)&1 == p (read next step, after barrier)
    if (t < TT && xloader) {
      const float4 v = *(const float4*)(x + ((size_t)b * TT + t) * II + xl * 4);
      xsl[p][xl * 2]     = pk16(v.x, v.y);
      xsl[p][xl * 2 + 1] = pk16(v.z, v.w);
    }

    if (t <= TT) {
      // ---- recurrent matvec: 8 rows x 64 k per thread ----
      float acc[8];
#pragma unroll
      for (int j = 0; j < 8; ++j) acc[j] = 0.0f;

#pragma unroll
      for (int blk = 0; blk < 3; ++blk) {   // 48 k from registers
        const uint4 h0v = *(const uint4*)&hsl[p][c][blk * 8];
        const uint4 h1v = *(const uint4*)&hsl[p][c][blk * 8 + 4];
#pragma unroll
        for (int j = 0; j < 8; ++j) {
          acc[j] = fdot2u(wh[j][blk * 8 + 0], h0v.x, acc[j]);
          acc[j] = fdot2u(wh[j][blk * 8 + 1], h0v.y, acc[j]);
          acc[j] = fdot2u(wh[j][blk * 8 + 2], h0v.z, acc[j]);
          acc[j] = fdot2u(wh[j][blk * 8 + 3], h0v.w, acc[j]);
          acc[j] = fdot2u(wh[j][blk * 8 + 4], h1v.x, acc[j]);
          acc[j] = fdot2u(wh[j][blk * 8 + 5], h1v.y, acc[j]);
          acc[j] = fdot2u(wh[j][blk * 8 + 6], h1v.z, acc[j]);
          acc[j] = fdot2u(wh[j][blk * 8 + 7], h1v.w, acc[j]);
        }
      }
      {  // 16 k from LDS tail
        const uint4 h0v = *(const uint4*)&hsl[p][c][24];
        const uint4 h1v = *(const uint4*)&hsl[p][c][28];
        const unsigned hx[8] = {h0v.x, h0v.y, h0v.z, h0v.w,
                                h1v.x, h1v.y, h1v.z, h1v.w};
#pragma unroll
        for (int mm = 0; mm < 16; ++mm) {
          const uint4 wv = *(const uint4*)&ldsW[mm][tid][0];
          const unsigned wa[4] = {wv.x, wv.y, wv.z, wv.w};
#pragma unroll
          for (int e = 0; e < 4; ++e) {
            const int idx = mm * 4 + e;
            acc[idx >> 3] = fdot2u(wa[e], hx[idx & 7], acc[idx >> 3]);
          }
        }
      }
      // reduce over k-chunks (8 lanes, xor butterfly)
#pragma unroll
      for (int m = 1; m < 8; m <<= 1) {
#pragma unroll
        for (int j = 0; j < 8; ++j) acc[j] += __shfl_xor(acc[j], m);
      }
      // thread tid's row total = acc[c]
      float val = acc[0];
#pragma unroll
      for (int j = 1; j < 8; ++j) val = (c == j) ? acc[j] : val;

      // ---- x-projection: row tid, Wih f16 slice from global (L1/L2) ----
#pragma unroll
      for (int pass = 0; pass < 4; ++pass) {
        const uint4 a0 = *(const uint4*)(wip + pass * 8);
        const uint4 a1 = *(const uint4*)(wip + pass * 8 + 4);
        const uint4 b0 = *(const uint4*)&xsl[1 - p][pass * 8];
        const uint4 b1 = *(const uint4*)&xsl[1 - p][pass * 8 + 4];
        val = fdot2u(a0.x, b0.x, val); val = fdot2u(a0.y, b0.y, val);
        val = fdot2u(a0.z, b0.z, val); val = fdot2u(a0.w, b0.w, val);
        val = fdot2u(a1.x, b1.x, val); val = fdot2u(a1.y, b1.y, val);
        val = fdot2u(a1.z, b1.z, val); val = fdot2u(a1.w, b1.w, val);
      }

      const float hf = tanh_fast(val + bsum);
      // write h_t (f16 pairs) into slot t&1 == 1-p
      const float pv = __shfl_xor(hf, 1);
      if (!(tid & 1)) {
        const int m = tid >> 1;
        hsl[1 - p][m >> 5][m & 31] = pk16(hf, pv);
      }
      if (t == TT) {  // final hidden state (fp32)
        out[(size_t)BB * TT * OO + (size_t)b * HH + tid] = hf;
      }
    }

    // ---- out-projection for tau = t-1 (h_{t-1} in slot p, still live) ----
    if (t >= 2) {
      const int o = tid >> 3, kc = tid & 7;
      float s = 0.0f;
#pragma unroll
      for (int pass = 0; pass < 4; ++pass) {
        const uint4 a0 = *(const uint4*)(wop + pass * 8);
        const uint4 a1 = *(const uint4*)(wop + pass * 8 + 4);
        const uint4 b0 = *(const uint4*)&hsl[p][kc][pass * 8];
        const uint4 b1 = *(const uint4*)&hsl[p][kc][pass * 8 + 4];
        s = fdot2u(a0.x, b0.x, s); s = fdot2u(a0.y, b0.y, s);
        s = fdot2u(a0.z, b0.z, s); s = fdot2u(a0.w, b0.w, s);
        s = fdot2u(a1.x, b1.x, s); s = fdot2u(a1.y, b1.y, s);
        s = fdot2u(a1.z, b1.z, s); s = fdot2u(a1.w, b1.w, s);
      }
      s += __shfl_xor(s, 1);
      s += __shfl_xor(s, 2);
      s += __shfl_xor(s, 4);
      if (kc == 0) {
        outb[(size_t)(t - 2) * OO + o] = tanh_fast(s + bo);
      }
    }

    __syncthreads();
  }
}

extern "C" void kernel_launch(void* const* d_in, const int* in_sizes, int n_in,
                              void* d_out, int out_size, void* d_ws, size_t ws_size,
                              hipStream_t stream) {
  (void)in_sizes; (void)n_in; (void)out_size; (void)ws_size;
  const float* x    = (const float*)d_in[0];
  const float* h0   = (const float*)d_in[1];
  const float* Wih  = (const float*)d_in[2];
  const float* Whh  = (const float*)d_in[3];
  const float* bih  = (const float*)d_in[4];
  const float* bhh  = (const float*)d_in[5];
  const float* Wout = (const float*)d_in[6];
  const float* bout = (const float*)d_in[7];
  float* out = (float*)d_out;

  unsigned char* ws = (unsigned char*)d_ws;
  unsigned* wsWih  = (unsigned*)ws;              // 16384 u32 = 64 KB
  unsigned* wsWout = (unsigned*)(ws + 65536);    // 16384 u32 = 64 KB

  prep_pack<<<dim3(128), dim3(256), 0, stream>>>(Wih, Wout, wsWih, wsWout);
  rnn_onecu<<<dim3(64), dim3(512), 0, stream>>>(
      x, h0, Whh, bih, bhh, bout, wsWih, wsWout, out);
}